// Round 1
// baseline (595.260 us; speedup 1.0000x reference)
//
#include <hip/hip_runtime.h>
#include <hip/hip_bf16.h>
#include <math.h>

#define DIMC 512
#define NPT  4096
#define BATCH 16

typedef __bf16 bf16x4 __attribute__((ext_vector_type(4)));
typedef __bf16 bf16x8 __attribute__((ext_vector_type(8)));
typedef float  f32x4  __attribute__((ext_vector_type(4)));

typedef const __attribute__((address_space(1))) unsigned int guint;
typedef __attribute__((address_space(3))) unsigned int luint;

__device__ inline void gl_lds16(const void* g, void* l) {
  __builtin_amdgcn_global_load_lds((guint*)g, (luint*)l, 16, 0, 0);
}

// ---------------------------------------------------------------------------
// Generic NT GEMM, bf16 inputs: C[m,n] = alpha * sum_k A[m,k] * B[n,k]
// A: [M,K] row-major, B: [N,K] row-major (i.e. B^T), C: [M,N] row-major.
// 128x128 tile, BK=32, 256 threads (4 waves, each 64x64 via 4x4 of 16x16x32).
// ---------------------------------------------------------------------------
template <typename OUT_T>
__global__ __launch_bounds__(256, 2) void gemm_nt_bf16(
    const __bf16* __restrict__ A, const __bf16* __restrict__ B,
    OUT_T* __restrict__ C, int M, int N, int K,
    long sA, long sB, long sC, float alpha)
{
  const int b = blockIdx.z;
  A += (long)b * sA;  B += (long)b * sB;  C += (long)b * sC;
  const int m0 = blockIdx.y * 128, n0 = blockIdx.x * 128;

  __shared__ alignas(16) __bf16 As[128 * 32];
  __shared__ alignas(16) __bf16 Bs[128 * 32];

  const int tid  = threadIdx.x;
  const int wave = tid >> 6, lane = tid & 63;
  const int wr = wave >> 1, wc = wave & 1;
  const int q = lane >> 4, p = lane & 15;
  const int r4 = lane >> 2;            // 0..15: row within 16-row chunk
  const int koff = (lane & 3) * 8;     // 8 bf16 = 16B per lane

  f32x4 acc[4][4];
#pragma unroll
  for (int i = 0; i < 4; ++i)
#pragma unroll
    for (int j = 0; j < 4; ++j) acc[i][j] = (f32x4){0.f, 0.f, 0.f, 0.f};

  const __bf16* gA = A + (long)m0 * K;
  const __bf16* gB = B + (long)n0 * K;

  for (int k0 = 0; k0 < K; k0 += 32) {
    __syncthreads();   // previous iter's LDS reads done before overwrite
#pragma unroll
    for (int h = 0; h < 2; ++h) {
      const int chunk = wave + h * 4;  // 8 chunks of 16 rows each
      gl_lds16(gA + (long)(chunk * 16 + r4) * K + k0 + koff, &As[chunk * 512]);
      gl_lds16(gB + (long)(chunk * 16 + r4) * K + k0 + koff, &Bs[chunk * 512]);
    }
    __syncthreads();   // vmcnt(0) drain + barrier: LDS ready

    bf16x8 af[4], bfv[4];
#pragma unroll
    for (int i = 0; i < 4; ++i)
      af[i] = ((const bf16x8*)As)[(wr * 64 + i * 16 + p) * 4 + q];
#pragma unroll
    for (int j = 0; j < 4; ++j)
      bfv[j] = ((const bf16x8*)Bs)[(wc * 64 + j * 16 + p) * 4 + q];
#pragma unroll
    for (int i = 0; i < 4; ++i)
#pragma unroll
      for (int j = 0; j < 4; ++j)
        acc[i][j] = __builtin_amdgcn_mfma_f32_16x16x32_bf16(af[i], bfv[j], acc[i][j], 0, 0, 0);
  }

#pragma unroll
  for (int i = 0; i < 4; ++i) {
    const int row = m0 + wr * 64 + i * 16 + q * 4;
#pragma unroll
    for (int j = 0; j < 4; ++j) {
      const int col = n0 + wc * 64 + j * 16 + p;
#pragma unroll
      for (int r = 0; r < 4; ++r)
        C[(long)(row + r) * N + col] = (OUT_T)(acc[i][j][r] * alpha);
    }
  }
}

// ---------------------------------------------------------------------------
// NT GEMM, fp32 inputs converted to bf16 in staging (used for Gram x.x^T).
// ---------------------------------------------------------------------------
__global__ __launch_bounds__(256, 2) void gemm_nt_f32in(
    const float* __restrict__ A, const float* __restrict__ B,
    float* __restrict__ C, int M, int N, int K,
    long sA, long sB, long sC, float alpha)
{
  const int b = blockIdx.z;
  A += (long)b * sA;  B += (long)b * sB;  C += (long)b * sC;
  const int m0 = blockIdx.y * 128, n0 = blockIdx.x * 128;

  __shared__ alignas(16) __bf16 As[128 * 32];
  __shared__ alignas(16) __bf16 Bs[128 * 32];

  const int tid  = threadIdx.x;
  const int wave = tid >> 6, lane = tid & 63;
  const int wr = wave >> 1, wc = wave & 1;
  const int q = lane >> 4, p = lane & 15;

  f32x4 acc[4][4];
#pragma unroll
  for (int i = 0; i < 4; ++i)
#pragma unroll
    for (int j = 0; j < 4; ++j) acc[i][j] = (f32x4){0.f, 0.f, 0.f, 0.f};

  for (int k0 = 0; k0 < K; k0 += 32) {
    __syncthreads();
#pragma unroll
    for (int c = 0; c < 4; ++c) {
      const int g = c * 256 + tid;       // 1024 float4-groups per tile
      const int row = g >> 3, kg = g & 7;
      float4 va = *(const float4*)(A + (long)(m0 + row) * K + k0 + kg * 4);
      float4 vb = *(const float4*)(B + (long)(n0 + row) * K + k0 + kg * 4);
      bf16x4 wa = {(__bf16)va.x, (__bf16)va.y, (__bf16)va.z, (__bf16)va.w};
      bf16x4 wb = {(__bf16)vb.x, (__bf16)vb.y, (__bf16)vb.z, (__bf16)vb.w};
      *(bf16x4*)&As[row * 32 + kg * 4] = wa;
      *(bf16x4*)&Bs[row * 32 + kg * 4] = wb;
    }
    __syncthreads();

    bf16x8 af[4], bfv[4];
#pragma unroll
    for (int i = 0; i < 4; ++i)
      af[i] = ((const bf16x8*)As)[(wr * 64 + i * 16 + p) * 4 + q];
#pragma unroll
    for (int j = 0; j < 4; ++j)
      bfv[j] = ((const bf16x8*)Bs)[(wc * 64 + j * 16 + p) * 4 + q];
#pragma unroll
    for (int i = 0; i < 4; ++i)
#pragma unroll
      for (int j = 0; j < 4; ++j)
        acc[i][j] = __builtin_amdgcn_mfma_f32_16x16x32_bf16(af[i], bfv[j], acc[i][j], 0, 0, 0);
  }

#pragma unroll
  for (int i = 0; i < 4; ++i) {
    const int row = m0 + wr * 64 + i * 16 + q * 4;
#pragma unroll
    for (int j = 0; j < 4; ++j) {
      const int col = n0 + wc * 64 + j * 16 + p;
#pragma unroll
      for (int r = 0; r < 4; ++r)
        C[(long)(row + r) * N + col] = acc[i][j][r] * alpha;
    }
  }
}

// ---------------------------------------------------------------------------
// NT GEMM, fp32 inputs, 3-term bf16 hi/lo split (fp32-accurate logit path):
// A = Ah + Al, B = Bh + Bl;  C ~= Ah.Bh + Ah.Bl + Al.Bh
// ---------------------------------------------------------------------------
__global__ __launch_bounds__(256, 2) void gemm_nt_split(
    const float* __restrict__ A, const float* __restrict__ B,
    float* __restrict__ C, int M, int N, int K,
    long sA, long sB, long sC, float alpha)
{
  const int b = blockIdx.z;
  A += (long)b * sA;  B += (long)b * sB;  C += (long)b * sC;
  const int m0 = blockIdx.y * 128, n0 = blockIdx.x * 128;

  __shared__ alignas(16) __bf16 Ah[128 * 32];
  __shared__ alignas(16) __bf16 Al[128 * 32];
  __shared__ alignas(16) __bf16 Bh[128 * 32];
  __shared__ alignas(16) __bf16 Bl[128 * 32];

  const int tid  = threadIdx.x;
  const int wave = tid >> 6, lane = tid & 63;
  const int wr = wave >> 1, wc = wave & 1;
  const int q = lane >> 4, p = lane & 15;

  f32x4 acc[4][4];
#pragma unroll
  for (int i = 0; i < 4; ++i)
#pragma unroll
    for (int j = 0; j < 4; ++j) acc[i][j] = (f32x4){0.f, 0.f, 0.f, 0.f};

  for (int k0 = 0; k0 < K; k0 += 32) {
    __syncthreads();
#pragma unroll
    for (int c = 0; c < 4; ++c) {
      const int g = c * 256 + tid;
      const int row = g >> 3, kg = g & 7;
      float4 va = *(const float4*)(A + (long)(m0 + row) * K + k0 + kg * 4);
      float4 vb = *(const float4*)(B + (long)(n0 + row) * K + k0 + kg * 4);
      bf16x4 ah, al, bh, bl;
#pragma unroll
      for (int e = 0; e < 4; ++e) {
        float fa = (e == 0) ? va.x : (e == 1) ? va.y : (e == 2) ? va.z : va.w;
        float fb = (e == 0) ? vb.x : (e == 1) ? vb.y : (e == 2) ? vb.z : vb.w;
        __bf16 hA = (__bf16)fa;  ah[e] = hA;  al[e] = (__bf16)(fa - (float)hA);
        __bf16 hB = (__bf16)fb;  bh[e] = hB;  bl[e] = (__bf16)(fb - (float)hB);
      }
      *(bf16x4*)&Ah[row * 32 + kg * 4] = ah;
      *(bf16x4*)&Al[row * 32 + kg * 4] = al;
      *(bf16x4*)&Bh[row * 32 + kg * 4] = bh;
      *(bf16x4*)&Bl[row * 32 + kg * 4] = bl;
    }
    __syncthreads();

    bf16x8 afh[4], afl[4], bfh[4], bfl[4];
#pragma unroll
    for (int i = 0; i < 4; ++i) {
      const int idx = (wr * 64 + i * 16 + p) * 4 + q;
      afh[i] = ((const bf16x8*)Ah)[idx];
      afl[i] = ((const bf16x8*)Al)[idx];
    }
#pragma unroll
    for (int j = 0; j < 4; ++j) {
      const int idx = (wc * 64 + j * 16 + p) * 4 + q;
      bfh[j] = ((const bf16x8*)Bh)[idx];
      bfl[j] = ((const bf16x8*)Bl)[idx];
    }
#pragma unroll
    for (int i = 0; i < 4; ++i)
#pragma unroll
      for (int j = 0; j < 4; ++j) {
        acc[i][j] = __builtin_amdgcn_mfma_f32_16x16x32_bf16(afh[i], bfh[j], acc[i][j], 0, 0, 0);
        acc[i][j] = __builtin_amdgcn_mfma_f32_16x16x32_bf16(afh[i], bfl[j], acc[i][j], 0, 0, 0);
        acc[i][j] = __builtin_amdgcn_mfma_f32_16x16x32_bf16(afl[i], bfh[j], acc[i][j], 0, 0, 0);
      }
  }

#pragma unroll
  for (int i = 0; i < 4; ++i) {
    const int row = m0 + wr * 64 + i * 16 + q * 4;
#pragma unroll
    for (int j = 0; j < 4; ++j) {
      const int col = n0 + wc * 64 + j * 16 + p;
#pragma unroll
      for (int r = 0; r < 4; ++r)
        C[(long)(row + r) * N + col] = acc[i][j][r] * alpha;
    }
  }
}

// ---------------------------------------------------------------------------
// x [B,512,4096] fp32 -> xt [B,4096,512] bf16  (64x64 tiles via LDS)
// ---------------------------------------------------------------------------
__global__ __launch_bounds__(256) void transpose_x(
    const float* __restrict__ x, __bf16* __restrict__ xt)
{
  const int b = blockIdx.z;
  const int n0 = blockIdx.x * 64, c0 = blockIdx.y * 64;
  const float* X = x + (long)b * DIMC * NPT;
  __bf16* XT = xt + (long)b * NPT * DIMC;

  __shared__ alignas(16) __bf16 T[64][68];   // pad: 136B row stride

  const int t = threadIdx.x;
  const int nq = t & 15, cr = t >> 4;
#pragma unroll
  for (int pass = 0; pass < 4; ++pass) {
    const int c = pass * 16 + cr;
    float4 v = *(const float4*)(X + (long)(c0 + c) * NPT + n0 + nq * 4);
    bf16x4 w = {(__bf16)v.x, (__bf16)v.y, (__bf16)v.z, (__bf16)v.w};
    *(bf16x4*)&T[c][nq * 4] = w;
  }
  __syncthreads();
  const int cq = t & 7, nr = t >> 3;
#pragma unroll
  for (int pass = 0; pass < 2; ++pass) {
    const int n = pass * 32 + nr;
    bf16x8 o;
#pragma unroll
    for (int i = 0; i < 8; ++i) o[i] = T[cq * 8 + i][n];
    *(bf16x8*)(XT + (long)(n0 + n) * DIMC + c0 + cq * 8) = o;
  }
}

// ---------------------------------------------------------------------------
// Row softmax over 512 cols (S fp32 already scaled), output bf16 P
// one wave per row, 4 rows per block
// ---------------------------------------------------------------------------
__global__ __launch_bounds__(256) void softmax_rows(
    const float* __restrict__ S, __bf16* __restrict__ P)
{
  const int row = blockIdx.x * 4 + (threadIdx.x >> 6);
  const int lane = threadIdx.x & 63;
  const float4* s4 = (const float4*)(S + (long)row * DIMC);
  float4 a = s4[lane * 2], b = s4[lane * 2 + 1];
  float v[8] = {a.x, a.y, a.z, a.w, b.x, b.y, b.z, b.w};
  float m = v[0];
#pragma unroll
  for (int i = 1; i < 8; ++i) m = fmaxf(m, v[i]);
#pragma unroll
  for (int off = 32; off > 0; off >>= 1) m = fmaxf(m, __shfl_xor(m, off));
  float e[8], sum = 0.f;
#pragma unroll
  for (int i = 0; i < 8; ++i) { e[i] = expf(v[i] - m); sum += e[i]; }
#pragma unroll
  for (int off = 32; off > 0; off >>= 1) sum += __shfl_xor(sum, off);
  const float inv = 1.0f / sum;
  bf16x8 o;
#pragma unroll
  for (int i = 0; i < 8; ++i) o[i] = (__bf16)(e[i] * inv);
  ((bf16x8*)(P + (long)row * DIMC))[lane] = o;
}

// WvT[c,e] = bf16(Wv[e,c])
__global__ __launch_bounds__(256) void make_wvt(
    const float* __restrict__ Wv, __bf16* __restrict__ WvT)
{
  const int i = blockIdx.x * 256 + threadIdx.x;  // i = c*512 + e
  const int c = i >> 9, e = i & 511;
  WvT[i] = (__bf16)Wv[e * DIMC + c];
}

extern "C" void kernel_launch(void* const* d_in, const int* in_sizes, int n_in,
                              void* d_out, int out_size, void* d_ws, size_t ws_size,
                              hipStream_t stream)
{
  const float* x  = (const float*)d_in[0];
  const float* Wq = (const float*)d_in[1];
  const float* Wk = (const float*)d_in[2];
  const float* Wv = (const float*)d_in[3];
  float* out = (float*)d_out;

  char* ws = (char*)d_ws;
  size_t off = 0;
  auto alloc = [&](size_t bytes) -> void* {
    void* p = ws + off;
    off += (bytes + 255) & ~(size_t)255;
    return p;
  };
  __bf16* xt  = (__bf16*)alloc((size_t)BATCH * NPT * DIMC * 2);   // 67.1 MB
  float*  G   = (float*) alloc((size_t)BATCH * DIMC * DIMC * 4);  // 16.8 MB
  float*  H   = (float*) alloc((size_t)BATCH * DIMC * DIMC * 4);  // 16.8 MB
  float*  S   = (float*) alloc((size_t)BATCH * DIMC * DIMC * 4);  // 16.8 MB
  __bf16* P   = (__bf16*)alloc((size_t)BATCH * DIMC * DIMC * 2);  //  8.4 MB
  __bf16* Mm  = (__bf16*)alloc((size_t)BATCH * DIMC * DIMC * 2);  //  8.4 MB
  __bf16* WvT = (__bf16*)alloc((size_t)DIMC * DIMC * 2);          //  0.5 MB

  const long s2 = (long)DIMC * DIMC;

  // Wv^T in bf16
  make_wvt<<<DIMC * DIMC / 256, 256, 0, stream>>>(Wv, WvT);
  // xt = x^T (bf16)
  transpose_x<<<dim3(NPT / 64, DIMC / 64, BATCH), 256, 0, stream>>>(x, xt);
  // G_b = x_b x_b^T  (fp32 out, bf16 MFMA)
  gemm_nt_f32in<<<dim3(4, 4, BATCH), 256, 0, stream>>>(
      x, x, G, DIMC, DIMC, NPT, (long)DIMC * NPT, (long)DIMC * NPT, s2, 1.0f);
  // H_b[d,c'] = sum_c Wq[d,c] G_b[c',c]   (G symmetric -> NT; split precision)
  gemm_nt_split<<<dim3(4, 4, BATCH), 256, 0, stream>>>(
      Wq, G, H, DIMC, DIMC, DIMC, 0L, s2, s2, 1.0f);
  // S_b[d,e] = (1/sqrt(512)) * sum_c' H_b[d,c'] Wk[e,c']
  gemm_nt_split<<<dim3(4, 4, BATCH), 256, 0, stream>>>(
      H, Wk, S, DIMC, DIMC, DIMC, s2, 0L, s2, 0.044194173824159216f);
  // P = softmax_rows(S)
  softmax_rows<<<BATCH * DIMC / 4, 256, 0, stream>>>(S, P);
  // M_b[d,c] = sum_e P_b[d,e] WvT[c,e]
  gemm_nt_bf16<__bf16><<<dim3(4, 4, BATCH), 256, 0, stream>>>(
      P, WvT, Mm, DIMC, DIMC, DIMC, s2, 0L, s2, 1.0f);
  // out_b[d,n] = sum_c M_b[d,c] xt_b[n,c]
  gemm_nt_bf16<float><<<dim3(NPT / 128, DIMC / 128, BATCH), 256, 0, stream>>>(
      Mm, xt, out, DIMC, NPT, DIMC, s2, (long)NPT * DIMC, (long)DIMC * NPT, 1.0f);
}

// Round 2
// 491.404 us; speedup vs baseline: 1.2113x; 1.2113x over previous
//
#include <hip/hip_runtime.h>
#include <hip/hip_bf16.h>
#include <math.h>

#define DIMC 512
#define NPT  4096
#define BATCH 16
#define KSPLIT 4

typedef __bf16 bf16x4 __attribute__((ext_vector_type(4)));
typedef __bf16 bf16x8 __attribute__((ext_vector_type(8)));
typedef float  f32x4  __attribute__((ext_vector_type(4)));

typedef const __attribute__((address_space(1))) unsigned int guint;
typedef __attribute__((address_space(3))) unsigned int luint;

__device__ inline void gl_lds16(const void* g, void* l) {
  __builtin_amdgcn_global_load_lds((guint*)g, (luint*)l, 16, 0, 0);
}

// ---------------------------------------------------------------------------
// NT GEMM, bf16 inputs: C[m,n] = alpha * sum_k A[m,k]*B[n,k]
// 128x128 tile, BK=32, 256 threads (4 waves, each 64x64 via 4x4 of 16x16x32).
// Used for the final out = M . x^T (M=512, N=4096, K=512), grid 2048 blocks.
// ---------------------------------------------------------------------------
template <typename OUT_T>
__global__ __launch_bounds__(256, 2) void gemm_nt_bf16(
    const __bf16* __restrict__ A, const __bf16* __restrict__ B,
    OUT_T* __restrict__ C, int M, int N, int K,
    long sA, long sB, long sC, float alpha)
{
  const int b = blockIdx.z;
  A += (long)b * sA;  B += (long)b * sB;  C += (long)b * sC;
  const int m0 = blockIdx.y * 128, n0 = blockIdx.x * 128;

  __shared__ alignas(16) __bf16 As[128 * 32];
  __shared__ alignas(16) __bf16 Bs[128 * 32];

  const int tid  = threadIdx.x;
  const int wave = tid >> 6, lane = tid & 63;
  const int wr = wave >> 1, wc = wave & 1;
  const int q = lane >> 4, p = lane & 15;
  const int r4 = lane >> 2;
  const int koff = (lane & 3) * 8;

  f32x4 acc[4][4];
#pragma unroll
  for (int i = 0; i < 4; ++i)
#pragma unroll
    for (int j = 0; j < 4; ++j) acc[i][j] = (f32x4){0.f, 0.f, 0.f, 0.f};

  const __bf16* gA = A + (long)m0 * K;
  const __bf16* gB = B + (long)n0 * K;

  for (int k0 = 0; k0 < K; k0 += 32) {
    __syncthreads();
#pragma unroll
    for (int h = 0; h < 2; ++h) {
      const int chunk = wave + h * 4;
      gl_lds16(gA + (long)(chunk * 16 + r4) * K + k0 + koff, &As[chunk * 512]);
      gl_lds16(gB + (long)(chunk * 16 + r4) * K + k0 + koff, &Bs[chunk * 512]);
    }
    __syncthreads();

    bf16x8 af[4], bfv[4];
#pragma unroll
    for (int i = 0; i < 4; ++i)
      af[i] = ((const bf16x8*)As)[(wr * 64 + i * 16 + p) * 4 + q];
#pragma unroll
    for (int j = 0; j < 4; ++j)
      bfv[j] = ((const bf16x8*)Bs)[(wc * 64 + j * 16 + p) * 4 + q];
#pragma unroll
    for (int i = 0; i < 4; ++i)
#pragma unroll
      for (int j = 0; j < 4; ++j)
        acc[i][j] = __builtin_amdgcn_mfma_f32_16x16x32_bf16(af[i], bfv[j], acc[i][j], 0, 0, 0);
  }

#pragma unroll
  for (int i = 0; i < 4; ++i) {
    const int row = m0 + wr * 64 + i * 16 + q * 4;
#pragma unroll
    for (int j = 0; j < 4; ++j) {
      const int col = n0 + wc * 64 + j * 16 + p;
#pragma unroll
      for (int r = 0; r < 4; ++r)
        C[(long)(row + r) * N + col] = (OUT_T)(acc[i][j][r] * alpha);
    }
  }
}

// ---------------------------------------------------------------------------
// Gram with split-K: Gp[s][b] = xb_b[:, s*1024:(s+1)*1024] . (same)^T
// xb: [B,512,4096] bf16. 128x128 tile, grid (4,4,B*KSPLIT) = 1024 blocks.
// ---------------------------------------------------------------------------
__global__ __launch_bounds__(256, 4) void gram_split(
    const __bf16* __restrict__ xb, float* __restrict__ Gp)
{
  const int z = blockIdx.z;
  const int b = z >> 2, s = z & 3;            // KSPLIT = 4
  const __bf16* A = xb + (long)b * DIMC * NPT;
  float* C = Gp + ((long)s * BATCH + b) * DIMC * DIMC;
  const int m0 = blockIdx.y * 128, n0 = blockIdx.x * 128;

  __shared__ alignas(16) __bf16 As[128 * 32];
  __shared__ alignas(16) __bf16 Bs[128 * 32];

  const int tid  = threadIdx.x;
  const int wave = tid >> 6, lane = tid & 63;
  const int wr = wave >> 1, wc = wave & 1;
  const int q = lane >> 4, p = lane & 15;
  const int r4 = lane >> 2;
  const int koff = (lane & 3) * 8;

  f32x4 acc[4][4];
#pragma unroll
  for (int i = 0; i < 4; ++i)
#pragma unroll
    for (int j = 0; j < 4; ++j) acc[i][j] = (f32x4){0.f, 0.f, 0.f, 0.f};

  const __bf16* gA = A + (long)m0 * NPT;
  const __bf16* gB = A + (long)n0 * NPT;
  const int kbeg = s * (NPT / KSPLIT), kend = kbeg + NPT / KSPLIT;

  for (int k0 = kbeg; k0 < kend; k0 += 32) {
    __syncthreads();
#pragma unroll
    for (int h = 0; h < 2; ++h) {
      const int chunk = wave + h * 4;
      gl_lds16(gA + (long)(chunk * 16 + r4) * NPT + k0 + koff, &As[chunk * 512]);
      gl_lds16(gB + (long)(chunk * 16 + r4) * NPT + k0 + koff, &Bs[chunk * 512]);
    }
    __syncthreads();

    bf16x8 af[4], bfv[4];
#pragma unroll
    for (int i = 0; i < 4; ++i)
      af[i] = ((const bf16x8*)As)[(wr * 64 + i * 16 + p) * 4 + q];
#pragma unroll
    for (int j = 0; j < 4; ++j)
      bfv[j] = ((const bf16x8*)Bs)[(wc * 64 + j * 16 + p) * 4 + q];
#pragma unroll
    for (int i = 0; i < 4; ++i)
#pragma unroll
      for (int j = 0; j < 4; ++j)
        acc[i][j] = __builtin_amdgcn_mfma_f32_16x16x32_bf16(af[i], bfv[j], acc[i][j], 0, 0, 0);
  }

#pragma unroll
  for (int i = 0; i < 4; ++i) {
    const int row = m0 + wr * 64 + i * 16 + q * 4;
#pragma unroll
    for (int j = 0; j < 4; ++j) {
      const int col = n0 + wc * 64 + j * 16 + p;
#pragma unroll
      for (int r = 0; r < 4; ++r)
        C[(long)(row + r) * DIMC + col] = acc[i][j][r];
    }
  }
}

// Gp[4][B*512*512] -> G (sum over 4)
__global__ __launch_bounds__(256) void gram_reduce(
    const float4* __restrict__ Gp, float4* __restrict__ G)
{
  const long n4 = (long)BATCH * DIMC * DIMC / 4;
  const long i = (long)blockIdx.x * 256 + threadIdx.x;
  float4 a = Gp[i], b = Gp[i + n4], c = Gp[i + 2 * n4], d = Gp[i + 3 * n4];
  float4 r;
  r.x = (a.x + b.x) + (c.x + d.x);
  r.y = (a.y + b.y) + (c.y + d.y);
  r.z = (a.z + b.z) + (c.z + d.z);
  r.w = (a.w + b.w) + (c.w + d.w);
  G[i] = r;
}

// ---------------------------------------------------------------------------
// NT GEMM, fp32 inputs, 3-term bf16 hi/lo split, 64x64 tile (logit path).
// Grid (8,8,BATCH) = 1024 blocks; 4 waves, each 32x32 (2x2 of 16x16x32).
// ---------------------------------------------------------------------------
__global__ __launch_bounds__(256, 4) void gemm_nt_split64(
    const float* __restrict__ A, const float* __restrict__ B,
    float* __restrict__ C, int K,
    long sA, long sB, long sC, float alpha)
{
  const int b = blockIdx.z;
  A += (long)b * sA;  B += (long)b * sB;  C += (long)b * sC;
  const int m0 = blockIdx.y * 64, n0 = blockIdx.x * 64;

  __shared__ alignas(16) __bf16 Ah[64 * 32];
  __shared__ alignas(16) __bf16 Al[64 * 32];
  __shared__ alignas(16) __bf16 Bh[64 * 32];
  __shared__ alignas(16) __bf16 Bl[64 * 32];

  const int tid  = threadIdx.x;
  const int wave = tid >> 6, lane = tid & 63;
  const int wr = wave >> 1, wc = wave & 1;
  const int q = lane >> 4, p = lane & 15;

  f32x4 acc[2][2];
#pragma unroll
  for (int i = 0; i < 2; ++i)
#pragma unroll
    for (int j = 0; j < 2; ++j) acc[i][j] = (f32x4){0.f, 0.f, 0.f, 0.f};

  for (int k0 = 0; k0 < K; k0 += 32) {
    __syncthreads();
#pragma unroll
    for (int c = 0; c < 2; ++c) {
      const int g = c * 256 + tid;      // 512 float4-groups per 64x32 tile
      const int row = g >> 3, kg = g & 7;
      float4 va = *(const float4*)(A + (long)(m0 + row) * K + k0 + kg * 4);
      float4 vb = *(const float4*)(B + (long)(n0 + row) * K + k0 + kg * 4);
      bf16x4 ah, al, bh, bl;
#pragma unroll
      for (int e = 0; e < 4; ++e) {
        float fa = (e == 0) ? va.x : (e == 1) ? va.y : (e == 2) ? va.z : va.w;
        float fb = (e == 0) ? vb.x : (e == 1) ? vb.y : (e == 2) ? vb.z : vb.w;
        __bf16 hA = (__bf16)fa;  ah[e] = hA;  al[e] = (__bf16)(fa - (float)hA);
        __bf16 hB = (__bf16)fb;  bh[e] = hB;  bl[e] = (__bf16)(fb - (float)hB);
      }
      *(bf16x4*)&Ah[row * 32 + kg * 4] = ah;
      *(bf16x4*)&Al[row * 32 + kg * 4] = al;
      *(bf16x4*)&Bh[row * 32 + kg * 4] = bh;
      *(bf16x4*)&Bl[row * 32 + kg * 4] = bl;
    }
    __syncthreads();

    bf16x8 afh[2], afl[2], bfh[2], bfl[2];
#pragma unroll
    for (int i = 0; i < 2; ++i) {
      const int idx = (wr * 32 + i * 16 + p) * 4 + q;
      afh[i] = ((const bf16x8*)Ah)[idx];
      afl[i] = ((const bf16x8*)Al)[idx];
    }
#pragma unroll
    for (int j = 0; j < 2; ++j) {
      const int idx = (wc * 32 + j * 16 + p) * 4 + q;
      bfh[j] = ((const bf16x8*)Bh)[idx];
      bfl[j] = ((const bf16x8*)Bl)[idx];
    }
#pragma unroll
    for (int i = 0; i < 2; ++i)
#pragma unroll
      for (int j = 0; j < 2; ++j) {
        acc[i][j] = __builtin_amdgcn_mfma_f32_16x16x32_bf16(afh[i], bfh[j], acc[i][j], 0, 0, 0);
        acc[i][j] = __builtin_amdgcn_mfma_f32_16x16x32_bf16(afh[i], bfl[j], acc[i][j], 0, 0, 0);
        acc[i][j] = __builtin_amdgcn_mfma_f32_16x16x32_bf16(afl[i], bfh[j], acc[i][j], 0, 0, 0);
      }
  }

#pragma unroll
  for (int i = 0; i < 2; ++i) {
    const int row = m0 + wr * 32 + i * 16 + q * 4;
#pragma unroll
    for (int j = 0; j < 2; ++j) {
      const int col = n0 + wc * 32 + j * 16 + p;
#pragma unroll
      for (int r = 0; r < 4; ++r)
        C[(long)(row + r) * DIMC + col] = acc[i][j][r] * alpha;
    }
  }
}

// ---------------------------------------------------------------------------
// NT GEMM bf16, 64x64 tile with global_load_lds (for M = P . Wv^T).
// Grid (8,8,BATCH) = 1024 blocks.
// ---------------------------------------------------------------------------
__global__ __launch_bounds__(256, 4) void gemm_nt_bf16_64(
    const __bf16* __restrict__ A, const __bf16* __restrict__ B,
    __bf16* __restrict__ C, int K, long sA, long sB, long sC)
{
  const int b = blockIdx.z;
  A += (long)b * sA;  B += (long)b * sB;  C += (long)b * sC;
  const int m0 = blockIdx.y * 64, n0 = blockIdx.x * 64;

  __shared__ alignas(16) __bf16 As[64 * 32];
  __shared__ alignas(16) __bf16 Bs[64 * 32];

  const int tid  = threadIdx.x;
  const int wave = tid >> 6, lane = tid & 63;
  const int wr = wave >> 1, wc = wave & 1;
  const int q = lane >> 4, p = lane & 15;
  const int r4 = lane >> 2;          // 0..15
  const int koff = (lane & 3) * 8;

  f32x4 acc[2][2];
#pragma unroll
  for (int i = 0; i < 2; ++i)
#pragma unroll
    for (int j = 0; j < 2; ++j) acc[i][j] = (f32x4){0.f, 0.f, 0.f, 0.f};

  const __bf16* gA = A + (long)m0 * K;
  const __bf16* gB = B + (long)n0 * K;

  for (int k0 = 0; k0 < K; k0 += 32) {
    __syncthreads();
    // each wave stages 16 rows of A and 16 rows of B
    gl_lds16(gA + (long)(wave * 16 + r4) * K + k0 + koff, &As[wave * 512]);
    gl_lds16(gB + (long)(wave * 16 + r4) * K + k0 + koff, &Bs[wave * 512]);
    __syncthreads();

    bf16x8 af[2], bfv[2];
#pragma unroll
    for (int i = 0; i < 2; ++i)
      af[i] = ((const bf16x8*)As)[(wr * 32 + i * 16 + p) * 4 + q];
#pragma unroll
    for (int j = 0; j < 2; ++j)
      bfv[j] = ((const bf16x8*)Bs)[(wc * 32 + j * 16 + p) * 4 + q];
#pragma unroll
    for (int i = 0; i < 2; ++i)
#pragma unroll
      for (int j = 0; j < 2; ++j)
        acc[i][j] = __builtin_amdgcn_mfma_f32_16x16x32_bf16(af[i], bfv[j], acc[i][j], 0, 0, 0);
  }

#pragma unroll
  for (int i = 0; i < 2; ++i) {
    const int row = m0 + wr * 32 + i * 16 + q * 4;
#pragma unroll
    for (int j = 0; j < 2; ++j) {
      const int col = n0 + wc * 32 + j * 16 + p;
#pragma unroll
      for (int r = 0; r < 4; ++r)
        C[(long)(row + r) * DIMC + col] = (__bf16)acc[i][j][r];
    }
  }
}

// ---------------------------------------------------------------------------
// x [B,512,4096] fp32 -> xt [B,4096,512] bf16 AND xb [B,512,4096] bf16
// ---------------------------------------------------------------------------
__global__ __launch_bounds__(256) void transpose_convert_x(
    const float* __restrict__ x, __bf16* __restrict__ xt,
    __bf16* __restrict__ xb)
{
  const int b = blockIdx.z;
  const int n0 = blockIdx.x * 64, c0 = blockIdx.y * 64;
  const float* X = x + (long)b * DIMC * NPT;
  __bf16* XT = xt + (long)b * NPT * DIMC;
  __bf16* XB = xb + (long)b * DIMC * NPT;

  __shared__ alignas(16) __bf16 T[64][68];

  const int t = threadIdx.x;
  const int nq = t & 15, cr = t >> 4;
#pragma unroll
  for (int pass = 0; pass < 4; ++pass) {
    const int c = pass * 16 + cr;
    float4 v = *(const float4*)(X + (long)(c0 + c) * NPT + n0 + nq * 4);
    bf16x4 w = {(__bf16)v.x, (__bf16)v.y, (__bf16)v.z, (__bf16)v.w};
    *(bf16x4*)&T[c][nq * 4] = w;
    *(bf16x4*)(XB + (long)(c0 + c) * NPT + n0 + nq * 4) = w;
  }
  __syncthreads();
  const int cq = t & 7, nr = t >> 3;
#pragma unroll
  for (int pass = 0; pass < 2; ++pass) {
    const int n = pass * 32 + nr;
    bf16x8 o;
#pragma unroll
    for (int i = 0; i < 8; ++i) o[i] = T[cq * 8 + i][n];
    *(bf16x8*)(XT + (long)(n0 + n) * DIMC + c0 + cq * 8) = o;
  }
}

// ---------------------------------------------------------------------------
// Row softmax over 512 cols, fp32 in -> bf16 out. One wave per row.
// ---------------------------------------------------------------------------
__global__ __launch_bounds__(256) void softmax_rows(
    const float* __restrict__ S, __bf16* __restrict__ P)
{
  const int row = blockIdx.x * 4 + (threadIdx.x >> 6);
  const int lane = threadIdx.x & 63;
  const float4* s4 = (const float4*)(S + (long)row * DIMC);
  float4 a = s4[lane * 2], b = s4[lane * 2 + 1];
  float v[8] = {a.x, a.y, a.z, a.w, b.x, b.y, b.z, b.w};
  float m = v[0];
#pragma unroll
  for (int i = 1; i < 8; ++i) m = fmaxf(m, v[i]);
#pragma unroll
  for (int off = 32; off > 0; off >>= 1) m = fmaxf(m, __shfl_xor(m, off));
  float e[8], sum = 0.f;
#pragma unroll
  for (int i = 0; i < 8; ++i) { e[i] = expf(v[i] - m); sum += e[i]; }
#pragma unroll
  for (int off = 32; off > 0; off >>= 1) sum += __shfl_xor(sum, off);
  const float inv = 1.0f / sum;
  bf16x8 o;
#pragma unroll
  for (int i = 0; i < 8; ++i) o[i] = (__bf16)(e[i] * inv);
  ((bf16x8*)(P + (long)row * DIMC))[lane] = o;
}

// WvT[c,e] = bf16(Wv[e,c])
__global__ __launch_bounds__(256) void make_wvt(
    const float* __restrict__ Wv, __bf16* __restrict__ WvT)
{
  const int i = blockIdx.x * 256 + threadIdx.x;
  const int c = i >> 9, e = i & 511;
  WvT[i] = (__bf16)Wv[e * DIMC + c];
}

extern "C" void kernel_launch(void* const* d_in, const int* in_sizes, int n_in,
                              void* d_out, int out_size, void* d_ws, size_t ws_size,
                              hipStream_t stream)
{
  const float* x  = (const float*)d_in[0];
  const float* Wq = (const float*)d_in[1];
  const float* Wk = (const float*)d_in[2];
  const float* Wv = (const float*)d_in[3];
  float* out = (float*)d_out;

  char* ws = (char*)d_ws;
  size_t off = 0;
  auto alloc = [&](size_t bytes) -> void* {
    void* p = ws + off;
    off += (bytes + 255) & ~(size_t)255;
    return p;
  };
  __bf16* xt  = (__bf16*)alloc((size_t)BATCH * NPT * DIMC * 2);          // 67 MB
  __bf16* xb  = (__bf16*)alloc((size_t)BATCH * DIMC * NPT * 2);          // 67 MB
  float*  Gp  = (float*) alloc((size_t)KSPLIT * BATCH * DIMC * DIMC * 4);// 67 MB
  float*  G   = (float*) alloc((size_t)BATCH * DIMC * DIMC * 4);         // 17 MB
  float*  H   = (float*) alloc((size_t)BATCH * DIMC * DIMC * 4);         // 17 MB
  float*  S   = (float*) alloc((size_t)BATCH * DIMC * DIMC * 4);         // 17 MB
  __bf16* P   = (__bf16*)alloc((size_t)BATCH * DIMC * DIMC * 2);         //  8 MB
  __bf16* Mm  = (__bf16*)alloc((size_t)BATCH * DIMC * DIMC * 2);         //  8 MB
  __bf16* WvT = (__bf16*)alloc((size_t)DIMC * DIMC * 2);                 // 0.5 MB

  const long s2 = (long)DIMC * DIMC;

  make_wvt<<<DIMC * DIMC / 256, 256, 0, stream>>>(Wv, WvT);
  transpose_convert_x<<<dim3(NPT / 64, DIMC / 64, BATCH), 256, 0, stream>>>(x, xt, xb);
  // Gram, split-K x4, then reduce
  gram_split<<<dim3(4, 4, BATCH * KSPLIT), 256, 0, stream>>>(xb, Gp);
  gram_reduce<<<(int)((long)BATCH * DIMC * DIMC / 4 / 256), 256, 0, stream>>>(
      (const float4*)Gp, (float4*)G);
  // H_b[d,c'] = sum_c Wq[d,c] G_b[c',c]  (G symmetric -> NT, hi/lo split)
  gemm_nt_split64<<<dim3(8, 8, BATCH), 256, 0, stream>>>(
      Wq, G, H, DIMC, 0L, s2, s2, 1.0f);
  // S_b[d,e] = (1/sqrt(512)) sum_c' H_b[d,c'] Wk[e,c']
  gemm_nt_split64<<<dim3(8, 8, BATCH), 256, 0, stream>>>(
      H, Wk, S, DIMC, s2, 0L, s2, 0.044194173824159216f);
  softmax_rows<<<BATCH * DIMC / 4, 256, 0, stream>>>(S, P);
  // M_b[d,c] = sum_e P_b[d,e] WvT[c,e]
  gemm_nt_bf16_64<<<dim3(8, 8, BATCH), 256, 0, stream>>>(
      P, WvT, Mm, DIMC, s2, 0L, s2);
  // out_b[d,n] = sum_c M_b[d,c] xt_b[n,c]
  gemm_nt_bf16<float><<<dim3(NPT / 128, DIMC / 128, BATCH), 256, 0, stream>>>(
      Mm, xt, out, DIMC, NPT, DIMC, s2, (long)NPT * DIMC, (long)DIMC * NPT, 1.0f);
}

// Round 3
// 416.186 us; speedup vs baseline: 1.4303x; 1.1807x over previous
//
#include <hip/hip_runtime.h>
#include <hip/hip_bf16.h>
#include <math.h>

#define DIMC 512
#define NPT  4096
#define BATCH 16
#define KSPLIT 4

typedef __bf16 bf16x4 __attribute__((ext_vector_type(4)));
typedef __bf16 bf16x8 __attribute__((ext_vector_type(8)));
typedef float  f32x4  __attribute__((ext_vector_type(4)));

typedef const __attribute__((address_space(1))) unsigned int guint;
typedef __attribute__((address_space(3))) unsigned int luint;

__device__ inline void gl_lds16(const void* g, void* l) {
  __builtin_amdgcn_global_load_lds((guint*)g, (luint*)l, 16, 0, 0);
}

// ---------------------------------------------------------------------------
// Gram, upper-triangle 128-tiles only, split-K x4, XCD-swizzled 1D grid.
// id%8 = intended XCD; consecutive slots on one XCD walk tiles of one
// (b,s) pair so its 1MB xb slice stays L2-resident.
// Gp[pair][512][512] fp32, only tiles (i<=j) written.
// ---------------------------------------------------------------------------
__global__ __launch_bounds__(256, 4) void gram_split(
    const __bf16* __restrict__ xb, float* __restrict__ Gp)
{
  static const int TI[10] = {0,0,0,0,1,1,1,2,2,3};
  static const int TJ[10] = {0,1,2,3,1,2,3,2,3,3};
  const int id = blockIdx.x;              // 640 = 8 XCD * 8 pair-groups * 10 tiles
  const int xcd = id & 7, slot = id >> 3; // slot 0..79
  const int g = slot / 10, t = slot % 10;
  const int pair = xcd + 8 * g;           // 0..63
  const int b = pair >> 2, s = pair & 3;
  const int m0 = TI[t] * 128, n0 = TJ[t] * 128;

  const __bf16* A = xb + (long)b * DIMC * NPT;
  float* C = Gp + (long)pair * DIMC * DIMC;

  __shared__ alignas(16) __bf16 As[128 * 32];
  __shared__ alignas(16) __bf16 Bs[128 * 32];

  const int tid  = threadIdx.x;
  const int wave = tid >> 6, lane = tid & 63;
  const int wr = wave >> 1, wc = wave & 1;
  const int q = lane >> 4, p = lane & 15;
  const int r4 = lane >> 2;
  const int koff = (lane & 3) * 8;

  f32x4 acc[4][4];
#pragma unroll
  for (int i = 0; i < 4; ++i)
#pragma unroll
    for (int j = 0; j < 4; ++j) acc[i][j] = (f32x4){0.f, 0.f, 0.f, 0.f};

  const __bf16* gA = A + (long)m0 * NPT;
  const __bf16* gB = A + (long)n0 * NPT;
  const int kbeg = s * (NPT / KSPLIT), kend = kbeg + NPT / KSPLIT;

  for (int k0 = kbeg; k0 < kend; k0 += 32) {
    __syncthreads();
#pragma unroll
    for (int h = 0; h < 2; ++h) {
      const int chunk = wave + h * 4;
      gl_lds16(gA + (long)(chunk * 16 + r4) * NPT + k0 + koff, &As[chunk * 512]);
      gl_lds16(gB + (long)(chunk * 16 + r4) * NPT + k0 + koff, &Bs[chunk * 512]);
    }
    __syncthreads();

    bf16x8 af[4], bfv[4];
#pragma unroll
    for (int i = 0; i < 4; ++i)
      af[i] = ((const bf16x8*)As)[(wr * 64 + i * 16 + p) * 4 + q];
#pragma unroll
    for (int j = 0; j < 4; ++j)
      bfv[j] = ((const bf16x8*)Bs)[(wc * 64 + j * 16 + p) * 4 + q];
#pragma unroll
    for (int i = 0; i < 4; ++i)
#pragma unroll
      for (int j = 0; j < 4; ++j)
        acc[i][j] = __builtin_amdgcn_mfma_f32_16x16x32_bf16(af[i], bfv[j], acc[i][j], 0, 0, 0);
  }

#pragma unroll
  for (int i = 0; i < 4; ++i) {
    const int row = m0 + wr * 64 + i * 16 + q * 4;
#pragma unroll
    for (int j = 0; j < 4; ++j) {
      const int col = n0 + wc * 64 + j * 16 + p;
#pragma unroll
      for (int r = 0; r < 4; ++r)
        C[(long)(row + r) * DIMC + col] = acc[i][j][r];
    }
  }
}

// ---------------------------------------------------------------------------
// Reduce 4 split-K partials of each upper 64-tile (I<=J), emit Gh/Gl bf16
// hi/lo split, and mirror to the lower triangle via LDS transpose.
// Grid: BATCH * 36 blocks.
// ---------------------------------------------------------------------------
__global__ __launch_bounds__(256) void gram_reduce_mirror(
    const float* __restrict__ Gp, __bf16* __restrict__ Gh, __bf16* __restrict__ Gl)
{
  const int bid = blockIdx.x;
  const int b = bid / 36;
  int rem = bid % 36, I = 0;
  while (rem >= 8 - I) { rem -= 8 - I; ++I; }
  const int J = I + rem;

  __shared__ float T[64][65];
  const int tid = threadIdx.x;
  const int r = tid >> 2, c0 = (tid & 3) * 16;

  float v[16];
#pragma unroll
  for (int e = 0; e < 16; ++e) v[e] = 0.f;
#pragma unroll
  for (int s = 0; s < KSPLIT; ++s) {
    const float* src = Gp + (long)(b * KSPLIT + s) * DIMC * DIMC
                          + (long)(I * 64 + r) * DIMC + J * 64 + c0;
#pragma unroll
    for (int q = 0; q < 4; ++q) {
      float4 t4 = ((const float4*)src)[q];
      v[q * 4 + 0] += t4.x; v[q * 4 + 1] += t4.y;
      v[q * 4 + 2] += t4.z; v[q * 4 + 3] += t4.w;
    }
  }

  const long gbase = (long)b * DIMC * DIMC;
  // normal write
#pragma unroll
  for (int q = 0; q < 4; ++q) {
    bf16x4 h, l;
#pragma unroll
    for (int e = 0; e < 4; ++e) {
      float f = v[q * 4 + e];
      __bf16 hh = (__bf16)f;
      h[e] = hh; l[e] = (__bf16)(f - (float)hh);
    }
    const long o = gbase + (long)(I * 64 + r) * DIMC + J * 64 + c0 + q * 4;
    *(bf16x4*)(Gh + o) = h;
    *(bf16x4*)(Gl + o) = l;
  }
  // mirror write via LDS transpose
#pragma unroll
  for (int e = 0; e < 16; ++e) T[r][c0 + e] = v[e];
  __syncthreads();
  if (I != J) {
#pragma unroll
    for (int q = 0; q < 4; ++q) {
      bf16x4 h, l;
#pragma unroll
      for (int e = 0; e < 4; ++e) {
        float f = T[c0 + q * 4 + e][r];
        __bf16 hh = (__bf16)f;
        h[e] = hh; l[e] = (__bf16)(f - (float)hh);
      }
      const long o = gbase + (long)(J * 64 + r) * DIMC + I * 64 + c0 + q * 4;
      *(bf16x4*)(Gh + o) = h;
      *(bf16x4*)(Gl + o) = l;
    }
  }
}

// ---------------------------------------------------------------------------
// 3-term hi/lo NT GEMM, bf16 operands, 64x64 tile, gl_lds staging.
// C ~= (Ah+Al).(Bh+Bl)^T via Ah.Bh + Ah.Bl + Al.Bh.
// SPLIT_OUT: write hi/lo bf16 (Ch,Cl); else fp32 Cf with alpha.
// ---------------------------------------------------------------------------
template <bool SPLIT_OUT>
__global__ __launch_bounds__(256, 4) void gemm3_nt64(
    const __bf16* __restrict__ Ah, const __bf16* __restrict__ Al,
    const __bf16* __restrict__ Bh, const __bf16* __restrict__ Bl,
    float* __restrict__ Cf, __bf16* __restrict__ Ch, __bf16* __restrict__ Cl,
    int K, long sA, long sB, long sC, float alpha)
{
  const int b = blockIdx.z;
  Ah += (long)b * sA;  Al += (long)b * sA;
  Bh += (long)b * sB;  Bl += (long)b * sB;
  const int m0 = blockIdx.y * 64, n0 = blockIdx.x * 64;

  __shared__ alignas(16) __bf16 sAh[64 * 32], sAl[64 * 32];
  __shared__ alignas(16) __bf16 sBh[64 * 32], sBl[64 * 32];

  const int tid  = threadIdx.x;
  const int wave = tid >> 6, lane = tid & 63;
  const int wr = wave >> 1, wc = wave & 1;
  const int q = lane >> 4, p = lane & 15;
  const int r4 = lane >> 2;
  const int koff = (lane & 3) * 8;

  f32x4 acc[2][2];
#pragma unroll
  for (int i = 0; i < 2; ++i)
#pragma unroll
    for (int j = 0; j < 2; ++j) acc[i][j] = (f32x4){0.f, 0.f, 0.f, 0.f};

  const long arow = (long)(m0 + wave * 16 + r4) * K + koff;
  const long brow = (long)(n0 + wave * 16 + r4) * K + koff;

  for (int k0 = 0; k0 < K; k0 += 32) {
    __syncthreads();
    gl_lds16(Ah + arow + k0, &sAh[wave * 512]);
    gl_lds16(Al + arow + k0, &sAl[wave * 512]);
    gl_lds16(Bh + brow + k0, &sBh[wave * 512]);
    gl_lds16(Bl + brow + k0, &sBl[wave * 512]);
    __syncthreads();

    bf16x8 fah[2], fal[2], fbh[2], fbl[2];
#pragma unroll
    for (int i = 0; i < 2; ++i) {
      const int idx = (wr * 32 + i * 16 + p) * 4 + q;
      fah[i] = ((const bf16x8*)sAh)[idx];
      fal[i] = ((const bf16x8*)sAl)[idx];
    }
#pragma unroll
    for (int j = 0; j < 2; ++j) {
      const int idx = (wc * 32 + j * 16 + p) * 4 + q;
      fbh[j] = ((const bf16x8*)sBh)[idx];
      fbl[j] = ((const bf16x8*)sBl)[idx];
    }
#pragma unroll
    for (int i = 0; i < 2; ++i)
#pragma unroll
      for (int j = 0; j < 2; ++j) {
        acc[i][j] = __builtin_amdgcn_mfma_f32_16x16x32_bf16(fah[i], fbh[j], acc[i][j], 0, 0, 0);
        acc[i][j] = __builtin_amdgcn_mfma_f32_16x16x32_bf16(fah[i], fbl[j], acc[i][j], 0, 0, 0);
        acc[i][j] = __builtin_amdgcn_mfma_f32_16x16x32_bf16(fal[i], fbh[j], acc[i][j], 0, 0, 0);
      }
  }

#pragma unroll
  for (int i = 0; i < 2; ++i) {
    const int row = m0 + wr * 32 + i * 16 + q * 4;
#pragma unroll
    for (int j = 0; j < 2; ++j) {
      const int col = n0 + wc * 32 + j * 16 + p;
#pragma unroll
      for (int r = 0; r < 4; ++r) {
        const float f = acc[i][j][r] * alpha;
        const long o = (long)b * sC + (long)(row + r) * DIMC + col;
        if (SPLIT_OUT) {
          __bf16 hh = (__bf16)f;
          Ch[o] = hh;
          Cl[o] = (__bf16)(f - (float)hh);
        } else {
          Cf[o] = f;
        }
      }
    }
  }
}

// ---------------------------------------------------------------------------
// NT GEMM bf16, 64x64 tile (M = P . Wv^T). Grid (8,8,BATCH).
// ---------------------------------------------------------------------------
__global__ __launch_bounds__(256, 4) void gemm_nt_bf16_64(
    const __bf16* __restrict__ A, const __bf16* __restrict__ B,
    __bf16* __restrict__ C, int K, long sA, long sB, long sC)
{
  const int b = blockIdx.z;
  A += (long)b * sA;  B += (long)b * sB;  C += (long)b * sC;
  const int m0 = blockIdx.y * 64, n0 = blockIdx.x * 64;

  __shared__ alignas(16) __bf16 As[64 * 32];
  __shared__ alignas(16) __bf16 Bs[64 * 32];

  const int tid  = threadIdx.x;
  const int wave = tid >> 6, lane = tid & 63;
  const int wr = wave >> 1, wc = wave & 1;
  const int q = lane >> 4, p = lane & 15;
  const int r4 = lane >> 2;
  const int koff = (lane & 3) * 8;

  f32x4 acc[2][2];
#pragma unroll
  for (int i = 0; i < 2; ++i)
#pragma unroll
    for (int j = 0; j < 2; ++j) acc[i][j] = (f32x4){0.f, 0.f, 0.f, 0.f};

  const __bf16* gA = A + (long)m0 * K;
  const __bf16* gB = B + (long)n0 * K;

  for (int k0 = 0; k0 < K; k0 += 32) {
    __syncthreads();
    gl_lds16(gA + (long)(wave * 16 + r4) * K + k0 + koff, &As[wave * 512]);
    gl_lds16(gB + (long)(wave * 16 + r4) * K + k0 + koff, &Bs[wave * 512]);
    __syncthreads();

    bf16x8 af[2], bfv[2];
#pragma unroll
    for (int i = 0; i < 2; ++i)
      af[i] = ((const bf16x8*)As)[(wr * 32 + i * 16 + p) * 4 + q];
#pragma unroll
    for (int j = 0; j < 2; ++j)
      bfv[j] = ((const bf16x8*)Bs)[(wc * 32 + j * 16 + p) * 4 + q];
#pragma unroll
    for (int i = 0; i < 2; ++i)
#pragma unroll
      for (int j = 0; j < 2; ++j)
        acc[i][j] = __builtin_amdgcn_mfma_f32_16x16x32_bf16(af[i], bfv[j], acc[i][j], 0, 0, 0);
  }

#pragma unroll
  for (int i = 0; i < 2; ++i) {
    const int row = m0 + wr * 32 + i * 16 + q * 4;
#pragma unroll
    for (int j = 0; j < 2; ++j) {
      const int col = n0 + wc * 32 + j * 16 + p;
#pragma unroll
      for (int r = 0; r < 4; ++r)
        C[(long)(row + r) * DIMC + col] = (__bf16)acc[i][j][r];
    }
  }
}

// ---------------------------------------------------------------------------
// Final GEMM: out_b[d,n] = sum_c Mm_b[d,c] xt_b[n,c].  128x128 tile,
// XCD-swizzled 1D grid (2048): each batch's 4MB xt slice stays on one XCD.
// ---------------------------------------------------------------------------
__global__ __launch_bounds__(256, 2) void gemm_final(
    const __bf16* __restrict__ Mm, const __bf16* __restrict__ xt,
    float* __restrict__ out)
{
  const int id = blockIdx.x;
  const int xcd = id & 7, slot = id >> 3;   // slot 0..255
  const int g = slot >> 7, tile = slot & 127;
  const int b = xcd + 8 * g;
  const int m0 = (tile >> 5) * 128, n0 = (tile & 31) * 128;

  const __bf16* A = Mm + (long)b * DIMC * DIMC;
  const __bf16* B = xt + (long)b * NPT * DIMC;
  float* C = out + (long)b * DIMC * NPT;
  const int K = DIMC;

  __shared__ alignas(16) __bf16 As[128 * 32];
  __shared__ alignas(16) __bf16 Bs[128 * 32];

  const int tid  = threadIdx.x;
  const int wave = tid >> 6, lane = tid & 63;
  const int wr = wave >> 1, wc = wave & 1;
  const int q = lane >> 4, p = lane & 15;
  const int r4 = lane >> 2;
  const int koff = (lane & 3) * 8;

  f32x4 acc[4][4];
#pragma unroll
  for (int i = 0; i < 4; ++i)
#pragma unroll
    for (int j = 0; j < 4; ++j) acc[i][j] = (f32x4){0.f, 0.f, 0.f, 0.f};

  const __bf16* gA = A + (long)m0 * K;
  const __bf16* gB = B + (long)n0 * K;

  for (int k0 = 0; k0 < K; k0 += 32) {
    __syncthreads();
#pragma unroll
    for (int h = 0; h < 2; ++h) {
      const int chunk = wave + h * 4;
      gl_lds16(gA + (long)(chunk * 16 + r4) * K + k0 + koff, &As[chunk * 512]);
      gl_lds16(gB + (long)(chunk * 16 + r4) * K + k0 + koff, &Bs[chunk * 512]);
    }
    __syncthreads();

    bf16x8 af[4], bfv[4];
#pragma unroll
    for (int i = 0; i < 4; ++i)
      af[i] = ((const bf16x8*)As)[(wr * 64 + i * 16 + p) * 4 + q];
#pragma unroll
    for (int j = 0; j < 4; ++j)
      bfv[j] = ((const bf16x8*)Bs)[(wc * 64 + j * 16 + p) * 4 + q];
#pragma unroll
    for (int i = 0; i < 4; ++i)
#pragma unroll
      for (int j = 0; j < 4; ++j)
        acc[i][j] = __builtin_amdgcn_mfma_f32_16x16x32_bf16(af[i], bfv[j], acc[i][j], 0, 0, 0);
  }

#pragma unroll
  for (int i = 0; i < 4; ++i) {
    const int row = m0 + wr * 64 + i * 16 + q * 4;
#pragma unroll
    for (int j = 0; j < 4; ++j) {
      const int col = n0 + wc * 64 + j * 16 + p;
#pragma unroll
      for (int r = 0; r < 4; ++r)
        C[(long)(row + r) * NPT + col] = acc[i][j][r];
    }
  }
}

// ---------------------------------------------------------------------------
// x [B,512,4096] fp32 -> xt [B,4096,512] bf16 AND xb [B,512,4096] bf16
// ---------------------------------------------------------------------------
__global__ __launch_bounds__(256) void transpose_convert_x(
    const float* __restrict__ x, __bf16* __restrict__ xt,
    __bf16* __restrict__ xb)
{
  const int b = blockIdx.z;
  const int n0 = blockIdx.x * 64, c0 = blockIdx.y * 64;
  const float* X = x + (long)b * DIMC * NPT;
  __bf16* XT = xt + (long)b * NPT * DIMC;
  __bf16* XB = xb + (long)b * DIMC * NPT;

  __shared__ alignas(16) __bf16 T[64][68];

  const int t = threadIdx.x;
  const int nq = t & 15, cr = t >> 4;
#pragma unroll
  for (int pass = 0; pass < 4; ++pass) {
    const int c = pass * 16 + cr;
    float4 v = *(const float4*)(X + (long)(c0 + c) * NPT + n0 + nq * 4);
    bf16x4 w = {(__bf16)v.x, (__bf16)v.y, (__bf16)v.z, (__bf16)v.w};
    *(bf16x4*)&T[c][nq * 4] = w;
    *(bf16x4*)(XB + (long)(c0 + c) * NPT + n0 + nq * 4) = w;
  }
  __syncthreads();
  const int cq = t & 7, nr = t >> 3;
#pragma unroll
  for (int pass = 0; pass < 2; ++pass) {
    const int n = pass * 32 + nr;
    bf16x8 o;
#pragma unroll
    for (int i = 0; i < 8; ++i) o[i] = T[cq * 8 + i][n];
    *(bf16x8*)(XT + (long)(n0 + n) * DIMC + c0 + cq * 8) = o;
  }
}

// ---------------------------------------------------------------------------
// Row softmax over 512 cols, fp32 in -> bf16 out. One wave per row.
// ---------------------------------------------------------------------------
__global__ __launch_bounds__(256) void softmax_rows(
    const float* __restrict__ S, __bf16* __restrict__ P)
{
  const int row = blockIdx.x * 4 + (threadIdx.x >> 6);
  const int lane = threadIdx.x & 63;
  const float4* s4 = (const float4*)(S + (long)row * DIMC);
  float4 a = s4[lane * 2], b = s4[lane * 2 + 1];
  float v[8] = {a.x, a.y, a.z, a.w, b.x, b.y, b.z, b.w};
  float m = v[0];
#pragma unroll
  for (int i = 1; i < 8; ++i) m = fmaxf(m, v[i]);
#pragma unroll
  for (int off = 32; off > 0; off >>= 1) m = fmaxf(m, __shfl_xor(m, off));
  float e[8], sum = 0.f;
#pragma unroll
  for (int i = 0; i < 8; ++i) { e[i] = expf(v[i] - m); sum += e[i]; }
#pragma unroll
  for (int off = 32; off > 0; off >>= 1) sum += __shfl_xor(sum, off);
  const float inv = 1.0f / sum;
  bf16x8 o;
#pragma unroll
  for (int i = 0; i < 8; ++i) o[i] = (__bf16)(e[i] * inv);
  ((bf16x8*)(P + (long)row * DIMC))[lane] = o;
}

// ---------------------------------------------------------------------------
// Split Wq, Wk into bf16 hi/lo; WvT[c,e] = bf16(Wv[e,c]).
// ---------------------------------------------------------------------------
__global__ __launch_bounds__(256) void make_w(
    const float* __restrict__ Wq, const float* __restrict__ Wk,
    const float* __restrict__ Wv,
    __bf16* __restrict__ Wqh, __bf16* __restrict__ Wql,
    __bf16* __restrict__ Wkh, __bf16* __restrict__ Wkl,
    __bf16* __restrict__ WvT)
{
  const int i = blockIdx.x * 256 + threadIdx.x;
  float q = Wq[i];
  __bf16 qh = (__bf16)q; Wqh[i] = qh; Wql[i] = (__bf16)(q - (float)qh);
  float k = Wk[i];
  __bf16 kh = (__bf16)k; Wkh[i] = kh; Wkl[i] = (__bf16)(k - (float)kh);
  const int e = i >> 9, c = i & 511;
  WvT[(long)c * DIMC + e] = (__bf16)Wv[i];
}

extern "C" void kernel_launch(void* const* d_in, const int* in_sizes, int n_in,
                              void* d_out, int out_size, void* d_ws, size_t ws_size,
                              hipStream_t stream)
{
  const float* x  = (const float*)d_in[0];
  const float* Wq = (const float*)d_in[1];
  const float* Wk = (const float*)d_in[2];
  const float* Wv = (const float*)d_in[3];
  float* out = (float*)d_out;

  char* ws = (char*)d_ws;
  size_t off = 0;
  auto alloc = [&](size_t bytes) -> void* {
    void* p = ws + off;
    off += (bytes + 255) & ~(size_t)255;
    return p;
  };
  const long s2 = (long)DIMC * DIMC;

  __bf16* xt  = (__bf16*)alloc((size_t)BATCH * NPT * DIMC * 2);           // 67 MB
  __bf16* xb  = (__bf16*)alloc((size_t)BATCH * DIMC * NPT * 2);           // 67 MB
  float*  Gp  = (float*) alloc((size_t)KSPLIT * BATCH * s2 * 4);          // 67 MB
  __bf16* Gh  = (__bf16*)alloc((size_t)BATCH * s2 * 2);                   // 8.4 MB
  __bf16* Gl  = (__bf16*)alloc((size_t)BATCH * s2 * 2);
  __bf16* Hh  = (__bf16*)alloc((size_t)BATCH * s2 * 2);
  __bf16* Hl  = (__bf16*)alloc((size_t)BATCH * s2 * 2);
  __bf16* Wqh = (__bf16*)alloc((size_t)s2 * 2);
  __bf16* Wql = (__bf16*)alloc((size_t)s2 * 2);
  __bf16* Wkh = (__bf16*)alloc((size_t)s2 * 2);
  __bf16* Wkl = (__bf16*)alloc((size_t)s2 * 2);
  __bf16* WvT = (__bf16*)alloc((size_t)s2 * 2);
  // Aliases (lifetimes verified: Gp dead after reduce; Gl dead after H-GEMM;
  // Gh dead after H-GEMM):
  float*  S  = (float*)Gp;    // written by S-GEMM
  __bf16* P  = Gl;            // written by softmax
  __bf16* Mm = Gh;            // written by M-GEMM

  make_w<<<DIMC * DIMC / 256, 256, 0, stream>>>(Wq, Wk, Wv, Wqh, Wql, Wkh, Wkl, WvT);
  transpose_convert_x<<<dim3(NPT / 64, DIMC / 64, BATCH), 256, 0, stream>>>(x, xt, xb);
  // Gram: upper-triangle tiles, split-K, XCD swizzle
  gram_split<<<640, 256, 0, stream>>>(xb, Gp);
  gram_reduce_mirror<<<BATCH * 36, 256, 0, stream>>>(Gp, Gh, Gl);
  // H = Wq . G  (G symmetric -> NT), hi/lo 3-term, split output
  gemm3_nt64<true><<<dim3(8, 8, BATCH), 256, 0, stream>>>(
      Wqh, Wql, Gh, Gl, (float*)nullptr, Hh, Hl, DIMC, 0L, s2, s2, 1.0f);
  // S = (1/sqrt(512)) H . Wk^T, hi/lo 3-term, fp32 output
  gemm3_nt64<false><<<dim3(8, 8, BATCH), 256, 0, stream>>>(
      Hh, Hl, Wkh, Wkl, S, (__bf16*)nullptr, (__bf16*)nullptr,
      DIMC, s2, 0L, s2, 0.044194173824159216f);
  softmax_rows<<<BATCH * DIMC / 4, 256, 0, stream>>>(S, P);
  // M = P . Wv^T
  gemm_nt_bf16_64<<<dim3(8, 8, BATCH), 256, 0, stream>>>(
      P, WvT, Mm, DIMC, s2, 0L, s2);
  // out = M . x  (via xt, XCD-swizzled)
  gemm_final<<<2048, 256, 0, stream>>>(Mm, xt, out);
}

// Round 4
// 415.657 us; speedup vs baseline: 1.4321x; 1.0013x over previous
//
#include <hip/hip_runtime.h>
#include <hip/hip_bf16.h>
#include <math.h>

#define DIMC 512
#define NPT  4096
#define BATCH 16
#define KSPLIT 4

typedef __bf16 bf16x4 __attribute__((ext_vector_type(4)));
typedef __bf16 bf16x8 __attribute__((ext_vector_type(8)));
typedef float  f32x4  __attribute__((ext_vector_type(4)));

typedef const __attribute__((address_space(1))) unsigned int guint;
typedef __attribute__((address_space(3))) unsigned int luint;

__device__ inline void gl_lds16(const void* g, void* l) {
  __builtin_amdgcn_global_load_lds((guint*)g, (luint*)l, 16, 0, 0);
}

__device__ inline unsigned short bfbits(float f) {
  union { __bf16 h; unsigned short u; } cv;
  cv.h = (__bf16)f;
  return cv.u;
}

// ---------------------------------------------------------------------------
// Gram, upper-triangle 128-tiles only, split-K x4, XCD-swizzled 1D grid.
// ---------------------------------------------------------------------------
__global__ __launch_bounds__(256, 4) void gram_split(
    const __bf16* __restrict__ xb, float* __restrict__ Gp)
{
  static const int TI[10] = {0,0,0,0,1,1,1,2,2,3};
  static const int TJ[10] = {0,1,2,3,1,2,3,2,3,3};
  const int id = blockIdx.x;              // 640 = 8 XCD * 8 pair-groups * 10 tiles
  const int xcd = id & 7, slot = id >> 3;
  const int g = slot / 10, t = slot % 10;
  const int pair = xcd + 8 * g;
  const int b = pair >> 2, s = pair & 3;
  const int m0 = TI[t] * 128, n0 = TJ[t] * 128;

  const __bf16* A = xb + (long)b * DIMC * NPT;
  float* C = Gp + (long)pair * DIMC * DIMC;

  __shared__ alignas(16) __bf16 As[128 * 32];
  __shared__ alignas(16) __bf16 Bs[128 * 32];

  const int tid  = threadIdx.x;
  const int wave = tid >> 6, lane = tid & 63;
  const int wr = wave >> 1, wc = wave & 1;
  const int q = lane >> 4, p = lane & 15;
  const int r4 = lane >> 2;
  const int koff = (lane & 3) * 8;

  f32x4 acc[4][4];
#pragma unroll
  for (int i = 0; i < 4; ++i)
#pragma unroll
    for (int j = 0; j < 4; ++j) acc[i][j] = (f32x4){0.f, 0.f, 0.f, 0.f};

  const __bf16* gA = A + (long)m0 * NPT;
  const __bf16* gB = A + (long)n0 * NPT;
  const int kbeg = s * (NPT / KSPLIT), kend = kbeg + NPT / KSPLIT;

  for (int k0 = kbeg; k0 < kend; k0 += 32) {
    __syncthreads();
#pragma unroll
    for (int h = 0; h < 2; ++h) {
      const int chunk = wave + h * 4;
      gl_lds16(gA + (long)(chunk * 16 + r4) * NPT + k0 + koff, &As[chunk * 512]);
      gl_lds16(gB + (long)(chunk * 16 + r4) * NPT + k0 + koff, &Bs[chunk * 512]);
    }
    __syncthreads();

    bf16x8 af[4], bfv[4];
#pragma unroll
    for (int i = 0; i < 4; ++i)
      af[i] = ((const bf16x8*)As)[(wr * 64 + i * 16 + p) * 4 + q];
#pragma unroll
    for (int j = 0; j < 4; ++j)
      bfv[j] = ((const bf16x8*)Bs)[(wc * 64 + j * 16 + p) * 4 + q];
#pragma unroll
    for (int i = 0; i < 4; ++i)
#pragma unroll
      for (int j = 0; j < 4; ++j)
        acc[i][j] = __builtin_amdgcn_mfma_f32_16x16x32_bf16(af[i], bfv[j], acc[i][j], 0, 0, 0);
  }

#pragma unroll
  for (int i = 0; i < 4; ++i) {
    const int row = m0 + wr * 64 + i * 16 + q * 4;
#pragma unroll
    for (int j = 0; j < 4; ++j) {
      const int col = n0 + wc * 64 + j * 16 + p;
#pragma unroll
      for (int r = 0; r < 4; ++r)
        C[(long)(row + r) * DIMC + col] = acc[i][j][r];
    }
  }
}

// ---------------------------------------------------------------------------
// Reduce split-K partials of upper 64-tiles, emit Gh/Gl hi/lo, mirror lower.
// ---------------------------------------------------------------------------
__global__ __launch_bounds__(256) void gram_reduce_mirror(
    const float* __restrict__ Gp, __bf16* __restrict__ Gh, __bf16* __restrict__ Gl)
{
  const int bid = blockIdx.x;
  const int b = bid / 36;
  int rem = bid % 36, I = 0;
  while (rem >= 8 - I) { rem -= 8 - I; ++I; }
  const int J = I + rem;

  __shared__ float T[64][65];
  const int tid = threadIdx.x;
  const int r = tid >> 2, c0 = (tid & 3) * 16;

  float v[16];
#pragma unroll
  for (int e = 0; e < 16; ++e) v[e] = 0.f;
#pragma unroll
  for (int s = 0; s < KSPLIT; ++s) {
    const float* src = Gp + (long)(b * KSPLIT + s) * DIMC * DIMC
                          + (long)(I * 64 + r) * DIMC + J * 64 + c0;
#pragma unroll
    for (int q = 0; q < 4; ++q) {
      float4 t4 = ((const float4*)src)[q];
      v[q * 4 + 0] += t4.x; v[q * 4 + 1] += t4.y;
      v[q * 4 + 2] += t4.z; v[q * 4 + 3] += t4.w;
    }
  }

  const long gbase = (long)b * DIMC * DIMC;
#pragma unroll
  for (int q = 0; q < 4; ++q) {
    bf16x4 h, l;
#pragma unroll
    for (int e = 0; e < 4; ++e) {
      float f = v[q * 4 + e];
      __bf16 hh = (__bf16)f;
      h[e] = hh; l[e] = (__bf16)(f - (float)hh);
    }
    const long o = gbase + (long)(I * 64 + r) * DIMC + J * 64 + c0 + q * 4;
    *(bf16x4*)(Gh + o) = h;
    *(bf16x4*)(Gl + o) = l;
  }
#pragma unroll
  for (int e = 0; e < 16; ++e) T[r][c0 + e] = v[e];
  __syncthreads();
  if (I != J) {
#pragma unroll
    for (int q = 0; q < 4; ++q) {
      bf16x4 h, l;
#pragma unroll
      for (int e = 0; e < 4; ++e) {
        float f = T[c0 + q * 4 + e][r];
        __bf16 hh = (__bf16)f;
        h[e] = hh; l[e] = (__bf16)(f - (float)hh);
      }
      const long o = gbase + (long)(J * 64 + r) * DIMC + I * 64 + c0 + q * 4;
      *(bf16x4*)(Gh + o) = h;
      *(bf16x4*)(Gl + o) = l;
    }
  }
}

// ---------------------------------------------------------------------------
// 3-term hi/lo NT GEMM, 64M x 128N tile, BK=32, 4 waves (2x2, each 32x64).
// 6 gl_lds + 24 MFMA per K-iter. Grid (N/128, M/64, BATCH) = 512 blocks.
// ---------------------------------------------------------------------------
template <bool SPLIT_OUT>
__global__ __launch_bounds__(256, 4) void gemm3_nt(
    const __bf16* __restrict__ Ah, const __bf16* __restrict__ Al,
    const __bf16* __restrict__ Bh, const __bf16* __restrict__ Bl,
    float* __restrict__ Cf, __bf16* __restrict__ Ch, __bf16* __restrict__ Cl,
    int K, long sA, long sB, long sC, float alpha)
{
  const int b = blockIdx.z;
  Ah += (long)b * sA;  Al += (long)b * sA;
  Bh += (long)b * sB;  Bl += (long)b * sB;
  const int m0 = blockIdx.y * 64, n0 = blockIdx.x * 128;

  __shared__ alignas(16) __bf16 sAh[64 * 32],  sAl[64 * 32];
  __shared__ alignas(16) __bf16 sBh[128 * 32], sBl[128 * 32];

  const int tid  = threadIdx.x;
  const int wave = tid >> 6, lane = tid & 63;
  const int wr = wave >> 1, wc = wave & 1;
  const int q = lane >> 4, p = lane & 15;
  const int r4 = lane >> 2;
  const int koff = (lane & 3) * 8;

  f32x4 acc[2][4];
#pragma unroll
  for (int i = 0; i < 2; ++i)
#pragma unroll
    for (int j = 0; j < 4; ++j) acc[i][j] = (f32x4){0.f, 0.f, 0.f, 0.f};

  const long arow = (long)(m0 + wave * 16 + r4) * K + koff;

  for (int k0 = 0; k0 < K; k0 += 32) {
    __syncthreads();
    gl_lds16(Ah + arow + k0, &sAh[wave * 512]);
    gl_lds16(Al + arow + k0, &sAl[wave * 512]);
#pragma unroll
    for (int h = 0; h < 2; ++h) {
      const int chunk = wave + h * 4;
      const long brow = (long)(n0 + chunk * 16 + r4) * K + koff + k0;
      gl_lds16(Bh + brow, &sBh[chunk * 512]);
      gl_lds16(Bl + brow, &sBl[chunk * 512]);
    }
    __syncthreads();

    bf16x8 fah[2], fal[2], fbh[4], fbl[4];
#pragma unroll
    for (int i = 0; i < 2; ++i) {
      const int idx = (wr * 32 + i * 16 + p) * 4 + q;
      fah[i] = ((const bf16x8*)sAh)[idx];
      fal[i] = ((const bf16x8*)sAl)[idx];
    }
#pragma unroll
    for (int j = 0; j < 4; ++j) {
      const int idx = (wc * 64 + j * 16 + p) * 4 + q;
      fbh[j] = ((const bf16x8*)sBh)[idx];
      fbl[j] = ((const bf16x8*)sBl)[idx];
    }
#pragma unroll
    for (int i = 0; i < 2; ++i)
#pragma unroll
      for (int j = 0; j < 4; ++j) {
        acc[i][j] = __builtin_amdgcn_mfma_f32_16x16x32_bf16(fah[i], fbh[j], acc[i][j], 0, 0, 0);
        acc[i][j] = __builtin_amdgcn_mfma_f32_16x16x32_bf16(fah[i], fbl[j], acc[i][j], 0, 0, 0);
        acc[i][j] = __builtin_amdgcn_mfma_f32_16x16x32_bf16(fal[i], fbh[j], acc[i][j], 0, 0, 0);
      }
  }

#pragma unroll
  for (int i = 0; i < 2; ++i) {
    const int row = m0 + wr * 32 + i * 16 + q * 4;
#pragma unroll
    for (int j = 0; j < 4; ++j) {
      const int col = n0 + wc * 64 + j * 16 + p;
#pragma unroll
      for (int r = 0; r < 4; ++r) {
        const float f = acc[i][j][r] * alpha;
        const long o = (long)b * sC + (long)(row + r) * DIMC + col;
        if (SPLIT_OUT) {
          __bf16 hh = (__bf16)f;
          Ch[o] = hh;
          Cl[o] = (__bf16)(f - (float)hh);
        } else {
          Cf[o] = f;
        }
      }
    }
  }
}

// ---------------------------------------------------------------------------
// Single-term NT GEMM bf16, 64M x 128N tile (M = P . Wv^T). 3 gl_lds + 8 MFMA.
// ---------------------------------------------------------------------------
__global__ __launch_bounds__(256, 4) void gemm_nt64x128(
    const __bf16* __restrict__ A, const __bf16* __restrict__ B,
    __bf16* __restrict__ C, int K, long sA, long sB, long sC)
{
  const int b = blockIdx.z;
  A += (long)b * sA;  B += (long)b * sB;  C += (long)b * sC;
  const int m0 = blockIdx.y * 64, n0 = blockIdx.x * 128;

  __shared__ alignas(16) __bf16 As[64 * 32];
  __shared__ alignas(16) __bf16 Bs[128 * 32];

  const int tid  = threadIdx.x;
  const int wave = tid >> 6, lane = tid & 63;
  const int wr = wave >> 1, wc = wave & 1;
  const int q = lane >> 4, p = lane & 15;
  const int r4 = lane >> 2;
  const int koff = (lane & 3) * 8;

  f32x4 acc[2][4];
#pragma unroll
  for (int i = 0; i < 2; ++i)
#pragma unroll
    for (int j = 0; j < 4; ++j) acc[i][j] = (f32x4){0.f, 0.f, 0.f, 0.f};

  const long arow = (long)(m0 + wave * 16 + r4) * K + koff;

  for (int k0 = 0; k0 < K; k0 += 32) {
    __syncthreads();
    gl_lds16(A + arow + k0, &As[wave * 512]);
#pragma unroll
    for (int h = 0; h < 2; ++h) {
      const int chunk = wave + h * 4;
      gl_lds16(B + (long)(n0 + chunk * 16 + r4) * K + koff + k0, &Bs[chunk * 512]);
    }
    __syncthreads();

    bf16x8 af[2], bfv[4];
#pragma unroll
    for (int i = 0; i < 2; ++i)
      af[i] = ((const bf16x8*)As)[(wr * 32 + i * 16 + p) * 4 + q];
#pragma unroll
    for (int j = 0; j < 4; ++j)
      bfv[j] = ((const bf16x8*)Bs)[(wc * 64 + j * 16 + p) * 4 + q];
#pragma unroll
    for (int i = 0; i < 2; ++i)
#pragma unroll
      for (int j = 0; j < 4; ++j)
        acc[i][j] = __builtin_amdgcn_mfma_f32_16x16x32_bf16(af[i], bfv[j], acc[i][j], 0, 0, 0);
  }

#pragma unroll
  for (int i = 0; i < 2; ++i) {
    const int row = m0 + wr * 32 + i * 16 + q * 4;
#pragma unroll
    for (int j = 0; j < 4; ++j) {
      const int col = n0 + wc * 64 + j * 16 + p;
#pragma unroll
      for (int r = 0; r < 4; ++r)
        C[(long)(row + r) * DIMC + col] = (__bf16)acc[i][j][r];
    }
  }
}

// ---------------------------------------------------------------------------
// Final GEMM: out_b[d,n] = sum_c Mm_b[d,c] xt_b[n,c]. 128x128, XCD swizzle.
// ---------------------------------------------------------------------------
__global__ __launch_bounds__(256, 2) void gemm_final(
    const __bf16* __restrict__ Mm, const __bf16* __restrict__ xt,
    float* __restrict__ out)
{
  const int id = blockIdx.x;
  const int xcd = id & 7, slot = id >> 3;
  const int g = slot >> 7, tile = slot & 127;
  const int b = xcd + 8 * g;
  const int m0 = (tile >> 5) * 128, n0 = (tile & 31) * 128;

  const __bf16* A = Mm + (long)b * DIMC * DIMC;
  const __bf16* B = xt + (long)b * NPT * DIMC;
  float* C = out + (long)b * DIMC * NPT;
  const int K = DIMC;

  __shared__ alignas(16) __bf16 As[128 * 32];
  __shared__ alignas(16) __bf16 Bs[128 * 32];

  const int tid  = threadIdx.x;
  const int wave = tid >> 6, lane = tid & 63;
  const int wr = wave >> 1, wc = wave & 1;
  const int q = lane >> 4, p = lane & 15;
  const int r4 = lane >> 2;
  const int koff = (lane & 3) * 8;

  f32x4 acc[4][4];
#pragma unroll
  for (int i = 0; i < 4; ++i)
#pragma unroll
    for (int j = 0; j < 4; ++j) acc[i][j] = (f32x4){0.f, 0.f, 0.f, 0.f};

  const __bf16* gA = A + (long)m0 * K;
  const __bf16* gB = B + (long)n0 * K;

  for (int k0 = 0; k0 < K; k0 += 32) {
    __syncthreads();
#pragma unroll
    for (int h = 0; h < 2; ++h) {
      const int chunk = wave + h * 4;
      gl_lds16(gA + (long)(chunk * 16 + r4) * K + k0 + koff, &As[chunk * 512]);
      gl_lds16(gB + (long)(chunk * 16 + r4) * K + k0 + koff, &Bs[chunk * 512]);
    }
    __syncthreads();

    bf16x8 af[4], bfv[4];
#pragma unroll
    for (int i = 0; i < 4; ++i)
      af[i] = ((const bf16x8*)As)[(wr * 64 + i * 16 + p) * 4 + q];
#pragma unroll
    for (int j = 0; j < 4; ++j)
      bfv[j] = ((const bf16x8*)Bs)[(wc * 64 + j * 16 + p) * 4 + q];
#pragma unroll
    for (int i = 0; i < 4; ++i)
#pragma unroll
      for (int j = 0; j < 4; ++j)
        acc[i][j] = __builtin_amdgcn_mfma_f32_16x16x32_bf16(af[i], bfv[j], acc[i][j], 0, 0, 0);
  }

#pragma unroll
  for (int i = 0; i < 4; ++i) {
    const int row = m0 + wr * 64 + i * 16 + q * 4;
#pragma unroll
    for (int j = 0; j < 4; ++j) {
      const int col = n0 + wc * 64 + j * 16 + p;
#pragma unroll
      for (int r = 0; r < 4; ++r)
        C[(long)(row + r) * NPT + col] = acc[i][j][r];
    }
  }
}

// ---------------------------------------------------------------------------
// x [B,512,4096] fp32 -> xt [B,4096,512] bf16 AND xb [B,512,4096] bf16.
// Dword-pack transpose: LDS holds D[n][c/2] dwords ({c, c+1} bf16 pair).
// Writes: 8x ds_write_b32 (conflict-light); reads: 4x ds_read_b64 (bank-floor).
// ---------------------------------------------------------------------------
__global__ __launch_bounds__(256) void transpose_convert_x(
    const float* __restrict__ x, __bf16* __restrict__ xt,
    __bf16* __restrict__ xb)
{
  const int b = blockIdx.z;
  const int n0 = blockIdx.x * 64, c0 = blockIdx.y * 64;
  const float* X = x + (long)b * DIMC * NPT;
  __bf16* XT = xt + (long)b * NPT * DIMC;
  __bf16* XB = xb + (long)b * DIMC * NPT;

  __shared__ unsigned int D[64 * 34];   // [n][cp], row stride 34 dwords

  const int t = threadIdx.x;
  const int tn = t & 15;        // n-quad: n = tn*4 + i
  const int tc = t >> 4;        // c-pair index 0..15

#pragma unroll
  for (int pass = 0; pass < 2; ++pass) {
    const int c = pass * 32 + tc * 2;
    const float4 va = *(const float4*)(X + (long)(c0 + c) * NPT + n0 + tn * 4);
    const float4 vb = *(const float4*)(X + (long)(c0 + c + 1) * NPT + n0 + tn * 4);
    bf16x4 wa = {(__bf16)va.x, (__bf16)va.y, (__bf16)va.z, (__bf16)va.w};
    bf16x4 wb = {(__bf16)vb.x, (__bf16)vb.y, (__bf16)vb.z, (__bf16)vb.w};
    *(bf16x4*)(XB + (long)(c0 + c) * NPT + n0 + tn * 4) = wa;
    *(bf16x4*)(XB + (long)(c0 + c + 1) * NPT + n0 + tn * 4) = wb;
    const int cp = pass * 16 + tc;
    const float fa[4] = {va.x, va.y, va.z, va.w};
    const float fb[4] = {vb.x, vb.y, vb.z, vb.w};
#pragma unroll
    for (int i = 0; i < 4; ++i) {
      const unsigned int d = ((unsigned int)bfbits(fb[i]) << 16) | bfbits(fa[i]);
      D[(tn * 4 + i) * 34 + cp] = d;
    }
  }
  __syncthreads();

  const int n = t >> 2, ch = t & 3;
  const __bf16* Drow = (const __bf16*)&D[n * 34];
#pragma unroll
  for (int u = 0; u < 4; ++u) {
    const int unit = ch + u * 4;               // 0..15, 4 bf16 (= 2 dwords) each
    const uint2 w = *(const uint2*)(Drow + unit * 4);
    *(uint2*)(XT + (long)(n0 + n) * DIMC + c0 + unit * 4) = w;
  }
}

// ---------------------------------------------------------------------------
// Row softmax over 512 cols, fp32 in -> bf16 out. One wave per row.
// ---------------------------------------------------------------------------
__global__ __launch_bounds__(256) void softmax_rows(
    const float* __restrict__ S, __bf16* __restrict__ P)
{
  const int row = blockIdx.x * 4 + (threadIdx.x >> 6);
  const int lane = threadIdx.x & 63;
  const float4* s4 = (const float4*)(S + (long)row * DIMC);
  float4 a = s4[lane * 2], b = s4[lane * 2 + 1];
  float v[8] = {a.x, a.y, a.z, a.w, b.x, b.y, b.z, b.w};
  float m = v[0];
#pragma unroll
  for (int i = 1; i < 8; ++i) m = fmaxf(m, v[i]);
#pragma unroll
  for (int off = 32; off > 0; off >>= 1) m = fmaxf(m, __shfl_xor(m, off));
  float e[8], sum = 0.f;
#pragma unroll
  for (int i = 0; i < 8; ++i) { e[i] = expf(v[i] - m); sum += e[i]; }
#pragma unroll
  for (int off = 32; off > 0; off >>= 1) sum += __shfl_xor(sum, off);
  const float inv = 1.0f / sum;
  bf16x8 o;
#pragma unroll
  for (int i = 0; i < 8; ++i) o[i] = (__bf16)(e[i] * inv);
  ((bf16x8*)(P + (long)row * DIMC))[lane] = o;
}

// ---------------------------------------------------------------------------
// Split Wq, Wk into bf16 hi/lo; WvT[c,e] = bf16(Wv[e,c]).
// ---------------------------------------------------------------------------
__global__ __launch_bounds__(256) void make_w(
    const float* __restrict__ Wq, const float* __restrict__ Wk,
    const float* __restrict__ Wv,
    __bf16* __restrict__ Wqh, __bf16* __restrict__ Wql,
    __bf16* __restrict__ Wkh, __bf16* __restrict__ Wkl,
    __bf16* __restrict__ WvT)
{
  const int i = blockIdx.x * 256 + threadIdx.x;
  float q = Wq[i];
  __bf16 qh = (__bf16)q; Wqh[i] = qh; Wql[i] = (__bf16)(q - (float)qh);
  float k = Wk[i];
  __bf16 kh = (__bf16)k; Wkh[i] = kh; Wkl[i] = (__bf16)(k - (float)kh);
  const int e = i >> 9, c = i & 511;
  WvT[(long)c * DIMC + e] = (__bf16)Wv[i];
}

extern "C" void kernel_launch(void* const* d_in, const int* in_sizes, int n_in,
                              void* d_out, int out_size, void* d_ws, size_t ws_size,
                              hipStream_t stream)
{
  const float* x  = (const float*)d_in[0];
  const float* Wq = (const float*)d_in[1];
  const float* Wk = (const float*)d_in[2];
  const float* Wv = (const float*)d_in[3];
  float* out = (float*)d_out;

  char* ws = (char*)d_ws;
  size_t off = 0;
  auto alloc = [&](size_t bytes) -> void* {
    void* p = ws + off;
    off += (bytes + 255) & ~(size_t)255;
    return p;
  };
  const long s2 = (long)DIMC * DIMC;

  __bf16* xt  = (__bf16*)alloc((size_t)BATCH * NPT * DIMC * 2);
  __bf16* xb  = (__bf16*)alloc((size_t)BATCH * DIMC * NPT * 2);
  float*  Gp  = (float*) alloc((size_t)KSPLIT * BATCH * s2 * 4);
  __bf16* Gh  = (__bf16*)alloc((size_t)BATCH * s2 * 2);
  __bf16* Gl  = (__bf16*)alloc((size_t)BATCH * s2 * 2);
  __bf16* Hh  = (__bf16*)alloc((size_t)BATCH * s2 * 2);
  __bf16* Hl  = (__bf16*)alloc((size_t)BATCH * s2 * 2);
  __bf16* Wqh = (__bf16*)alloc((size_t)s2 * 2);
  __bf16* Wql = (__bf16*)alloc((size_t)s2 * 2);
  __bf16* Wkh = (__bf16*)alloc((size_t)s2 * 2);
  __bf16* Wkl = (__bf16*)alloc((size_t)s2 * 2);
  __bf16* WvT = (__bf16*)alloc((size_t)s2 * 2);
  float*  S  = (float*)Gp;    // alias: Gp dead after reduce
  __bf16* P  = Gl;            // alias: Gl dead after H-GEMM
  __bf16* Mm = Gh;            // alias: Gh dead after H-GEMM

  make_w<<<DIMC * DIMC / 256, 256, 0, stream>>>(Wq, Wk, Wv, Wqh, Wql, Wkh, Wkl, WvT);
  transpose_convert_x<<<dim3(NPT / 64, DIMC / 64, BATCH), 256, 0, stream>>>(x, xt, xb);
  gram_split<<<640, 256, 0, stream>>>(xb, Gp);
  gram_reduce_mirror<<<BATCH * 36, 256, 0, stream>>>(Gp, Gh, Gl);
  // H = Wq . G  (G symmetric -> NT), split output
  gemm3_nt<true><<<dim3(4, 8, BATCH), 256, 0, stream>>>(
      Wqh, Wql, Gh, Gl, (float*)nullptr, Hh, Hl, DIMC, 0L, s2, s2, 1.0f);
  // S = (1/sqrt(512)) H . Wk^T
  gemm3_nt<false><<<dim3(4, 8, BATCH), 256, 0, stream>>>(
      Hh, Hl, Wkh, Wkl, S, (__bf16*)nullptr, (__bf16*)nullptr,
      DIMC, s2, 0L, s2, 0.044194173824159216f);
  softmax_rows<<<BATCH * DIMC / 4, 256, 0, stream>>>(S, P);
  // M = P . Wv^T
  gemm_nt64x128<<<dim3(4, 8, BATCH), 256, 0, stream>>>(
      P, WvT, Mm, DIMC, s2, 0L, s2);
  // out = M . x (via xt)
  gemm_final<<<2048, 256, 0, stream>>>(Mm, xt, out);
}